// Round 1
// baseline (362.624 us; speedup 1.0000x reference)
//
#include <hip/hip_runtime.h>

typedef unsigned short u16;
typedef unsigned int   u32;
typedef __attribute__((ext_vector_type(4))) float f32x4;
typedef __attribute__((ext_vector_type(8))) short bf16x8;
typedef __attribute__((ext_vector_type(8))) unsigned short u16x8;
typedef __attribute__((ext_vector_type(4))) unsigned short u16x4;

#define MROWS 4096
#define DDIM  1024

__device__ __forceinline__ u16 f2bf(float f) {
  u32 u = __float_as_uint(f);
  u32 r = (u + 0x7FFFu + ((u >> 16) & 1u)) >> 16;   // RNE
  return (u16)r;
}
__device__ __forceinline__ float bf2f(u16 h) {
  return __uint_as_float(((u32)h) << 16);
}

// ---------------- expand + hi/lo split ----------------
// out[i][4k+{0..3}] = patA ? [hi,hi,lo,lo] : [hi,lo,hi,lo]
__global__ __launch_bounds__(256)
void expand_split(const float4* __restrict__ x, u16* __restrict__ out,
                  int n4, float scale, int patA) {
  int t = blockIdx.x * 256 + threadIdx.x;
  if (t >= n4) return;
  float4 v = x[t];
  float vv[4] = {v.x * scale, v.y * scale, v.z * scale, v.w * scale};
  u16 o[16];
#pragma unroll
  for (int j = 0; j < 4; ++j) {
    u16 h = f2bf(vv[j]);
    float hf = bf2f(h);
    u16 l = f2bf(vv[j] - hf);      // exact residual (Sterbenz), then RNE
    if (patA) { o[4*j+0]=h; o[4*j+1]=h; o[4*j+2]=l; o[4*j+3]=l; }
    else      { o[4*j+0]=h; o[4*j+1]=l; o[4*j+2]=h; o[4*j+3]=l; }
  }
  u16x8 a, b;
#pragma unroll
  for (int j = 0; j < 8; ++j) { a[j] = o[j]; b[j] = o[8 + j]; }
  u16x8* dst = (u16x8*)(out + (size_t)t * 16);
  dst[0] = a; dst[1] = b;
}

// ---------------- V transpose to bf16 (VT[d][k] = bf16(x2[k][d])) ----------------
__global__ __launch_bounds__(256)
void transpose_bf16(const float* __restrict__ x2, u16* __restrict__ VT) {
  __shared__ float tile[64][65];
  int tid = threadIdx.x;
  int dt = blockIdx.x;   // D tiles (16)
  int kt = blockIdx.y;   // K tiles (64)
#pragma unroll
  for (int it = 0; it < 16; ++it) {
    int lin = it * 256 + tid;
    int r = lin >> 6, c = lin & 63;
    tile[r][c] = x2[(size_t)(kt*64 + r) * DDIM + dt*64 + c];
  }
  __syncthreads();
#pragma unroll
  for (int it = 0; it < 16; ++it) {
    int lin = it * 256 + tid;
    int dr = lin >> 6, kc = lin & 63;
    VT[(size_t)(dt*64 + dr) * MROWS + kt*64 + kc] = f2bf(tile[kc][dr]);
  }
}

// ---------------- GEMM: C[M,N] = A[M,K] * Bt[N,K]^T  (m97 structure) ----------------
__device__ __forceinline__ void gload_lds16(const u16* g, u16* l) {
  __builtin_amdgcn_global_load_lds(
      (const __attribute__((address_space(1))) void*)g,
      (__attribute__((address_space(3))) void*)l, 16, 0, 0);
}

__global__ __launch_bounds__(256)
void gemm_bt(const u16* __restrict__ A, const u16* __restrict__ Bt,
             float* __restrict__ C, int M, int N, int K) {
  __shared__ u16 As[128 * 32];
  __shared__ u16 Bs[128 * 32];
  const int tid  = threadIdx.x;
  const int lane = tid & 63;
  const int w    = tid >> 6;
  const int wr = w >> 1, wc = w & 1;
  const long bm = (long)blockIdx.y * 128;
  const long bn = (long)blockIdx.x * 128;

  const f32x4 z = {0.0f, 0.0f, 0.0f, 0.0f};
  f32x4 acc[4][4];
#pragma unroll
  for (int m = 0; m < 4; ++m)
#pragma unroll
    for (int n = 0; n < 4; ++n) acc[m][n] = z;

  const int srow = tid >> 2;          // 0..63
  const int scol = (tid & 3) * 8;     // 0,8,16,24
  const u16* Ap = A  + (size_t)(bm + srow) * K + scol;
  const u16* Bp = Bt + (size_t)(bn + srow) * K + scol;
  u16* Asd = &As[tid * 8];            // linear LDS dest (wave-uniform base + lane*16B)
  u16* Bsd = &Bs[tid * 8];
  const size_t half = (size_t)64 * K;

  const int k8 = (lane >> 4) * 8;
  const int fr = lane & 15;

  for (int k0 = 0; k0 < K; k0 += 32) {
    gload_lds16(Ap + k0,        Asd);
    gload_lds16(Ap + k0 + half, Asd + 2048);
    gload_lds16(Bp + k0,        Bsd);
    gload_lds16(Bp + k0 + half, Bsd + 2048);
    __syncthreads();                   // drains vmcnt before barrier (compiler)
    bf16x8 a[4], b[4];
#pragma unroll
    for (int m = 0; m < 4; ++m)
      a[m] = *(const bf16x8*)&As[(wr*64 + m*16 + fr) * 32 + k8];
#pragma unroll
    for (int n = 0; n < 4; ++n)
      b[n] = *(const bf16x8*)&Bs[(wc*64 + n*16 + fr) * 32 + k8];
#pragma unroll
    for (int m = 0; m < 4; ++m)
#pragma unroll
      for (int n = 0; n < 4; ++n)
        acc[m][n] = __builtin_amdgcn_mfma_f32_16x16x32_bf16(a[m], b[n], acc[m][n], 0, 0, 0);
    __syncthreads();
  }

  // C/D layout: col = lane&15, row = (lane>>4)*4 + reg  [verified m89/m91]
  const int fq = lane >> 4;
  const long crow0 = bm + wr * 64;
  const long ccol0 = bn + wc * 64;
#pragma unroll
  for (int m = 0; m < 4; ++m)
#pragma unroll
    for (int n = 0; n < 4; ++n)
#pragma unroll
      for (int r = 0; r < 4; ++r)
        C[(size_t)(crow0 + m*16 + fq*4 + r) * N + (ccol0 + n*16 + fr)] = acc[m][n][r];
}

// ---------------- softmax + JAX-threefry dropout -> bf16 P ----------------
__device__ __forceinline__ u32 rotl32(u32 x, int r) { return (x << r) | (x >> (32 - r)); }

// JAX partitionable threefry random bits for flat index n (uint64 idx, hi=0):
// (o0,o1) = threefry2x32(key=(0,42), x=(0,n)); bits = o0 ^ o1
__device__ __forceinline__ u32 threefry_bits(u32 n) {
  const u32 K0 = 0u, K1 = 42u, K2 = 0x1BD11BDAu ^ 0u ^ 42u;
  u32 x0 = K0;          // counts_hi + ks[0]
  u32 x1 = n + K1;      // counts_lo + ks[1]
#define TF4(a,b,c,d) \
  x0 += x1; x1 = rotl32(x1, a); x1 ^= x0; \
  x0 += x1; x1 = rotl32(x1, b); x1 ^= x0; \
  x0 += x1; x1 = rotl32(x1, c); x1 ^= x0; \
  x0 += x1; x1 = rotl32(x1, d); x1 ^= x0;
  TF4(13,15,26,6);  x0 += K1; x1 += K2 + 1u;
  TF4(17,29,16,24); x0 += K2; x1 += K0 + 2u;
  TF4(13,15,26,6);  x0 += K0; x1 += K1 + 3u;
  TF4(17,29,16,24); x0 += K1; x1 += K2 + 4u;
  TF4(13,15,26,6);  x0 += K2; x1 += K0 + 5u;
#undef TF4
  return x0 ^ x1;
}

__global__ __launch_bounds__(256)
void softmax_dropout(const float* __restrict__ S, u16* __restrict__ P) {
  const int tid  = threadIdx.x;
  const int lane = tid & 63;
  const int w    = tid >> 6;
  const int row  = blockIdx.x * 4 + w;   // one row per wave
  const float4* Sr = (const float4*)(S + (size_t)row * MROWS);
  float4 v[16];
#pragma unroll
  for (int i = 0; i < 16; ++i) v[i] = Sr[i * 64 + lane];
  float m = -3.0e38f;
#pragma unroll
  for (int i = 0; i < 16; ++i)
    m = fmaxf(m, fmaxf(fmaxf(v[i].x, v[i].y), fmaxf(v[i].z, v[i].w)));
#pragma unroll
  for (int off = 32; off > 0; off >>= 1) m = fmaxf(m, __shfl_xor(m, off, 64));
  float s = 0.0f;
#pragma unroll
  for (int i = 0; i < 16; ++i) {
    v[i].x = __expf(v[i].x - m); v[i].y = __expf(v[i].y - m);
    v[i].z = __expf(v[i].z - m); v[i].w = __expf(v[i].w - m);
    s += v[i].x + v[i].y + v[i].z + v[i].w;
  }
#pragma unroll
  for (int off = 32; off > 0; off >>= 1) s += __shfl_xor(s, off, 64);
  const float inv = 2.0f / s;            // softmax normalize * 1/(1-p)
  u16* Pr = P + (size_t)row * MROWS;
#pragma unroll
  for (int i = 0; i < 16; ++i) {
    int j0 = (i * 64 + lane) * 4;
    u32 base = (u32)row * 4096u + (u32)j0;
    float e[4] = {v[i].x, v[i].y, v[i].z, v[i].w};
    u16x4 o;
#pragma unroll
    for (int c = 0; c < 4; ++c) {
      u32 bits = threefry_bits(base + (u32)c);
      // uniform<0.5  <=>  MSB==0 (exact)
      float val = (bits & 0x80000000u) ? 0.0f : e[c] * inv;
      o[c] = f2bf(val);
    }
    *(u16x4*)(Pr + j0) = o;
  }
}

// ---------------- launch ----------------
extern "C" void kernel_launch(void* const* d_in, const int* in_sizes, int n_in,
                              void* d_out, int out_size, void* d_ws, size_t ws_size,
                              hipStream_t stream) {
  const float* x1 = (const float*)d_in[0];
  const float* x2 = (const float*)d_in[1];
  float* out = (float*)d_out;
  char* ws = (char*)d_ws;

  // ws layout (bytes):
  //   XA 0..32MiB | XB 32..64MiB | VT 64..72MiB | S 72..136MiB ; P overlays XA
  const size_t OFF_XB = 33554432;
  const size_t OFF_VT = 67108864;
  const size_t OFF_S  = 75497472;
  const size_t NEED   = 142606336;
  if (ws_size < NEED) {
    // sentinel: make the failure unmistakable (absmax ~3.4e38 => ws too small)
    hipMemsetAsync(d_out, 0x7F, (size_t)out_size * sizeof(float), stream);
    return;
  }
  u16*  XA = (u16*)(ws);
  u16*  XB = (u16*)(ws + OFF_XB);
  u16*  VT = (u16*)(ws + OFF_VT);
  float* S = (float*)(ws + OFF_S);
  u16*  P  = (u16*)(ws);   // reuse XA region after GEMM1

  // scale 4.0 folded into x1's split (exact exponent shift)
  expand_split<<<4096, 256, 0, stream>>>((const float4*)x1, XA, 1048576, 4.0f, 1);
  expand_split<<<4096, 256, 0, stream>>>((const float4*)x2, XB, 1048576, 1.0f, 0);
  transpose_bf16<<<dim3(16, 64), 256, 0, stream>>>(x2, VT);
  // S = (4*x1) @ x2^T exactly via 4-way expanded K (hi/lo cross terms)
  gemm_bt<<<dim3(32, 32), 256, 0, stream>>>(XA, XB, S, 4096, 4096, 4096);
  softmax_dropout<<<1024, 256, 0, stream>>>(S, P);
  // O = P @ V  (Bt = VT[1024][4096])
  gemm_bt<<<dim3(8, 32), 256, 0, stream>>>(P, VT, out, 4096, 1024, 4096);
}

// Round 2
// 199.023 us; speedup vs baseline: 1.8220x; 1.8220x over previous
//
#include <hip/hip_runtime.h>

typedef unsigned short u16;
typedef unsigned int   u32;
typedef __attribute__((ext_vector_type(4))) float f32x4;
typedef __attribute__((ext_vector_type(8))) short bf16x8;
typedef __attribute__((ext_vector_type(8))) unsigned short u16x8;
typedef __attribute__((ext_vector_type(4))) unsigned short u16x4;

#define MROWS 4096
#define DDIM  1024

__device__ __forceinline__ u16 f2bf(float f) {
  u32 u = __float_as_uint(f);
  return (u16)((u + 0x7FFFu + ((u >> 16) & 1u)) >> 16);   // RNE
}
__device__ __forceinline__ float bf2f(u16 h) { return __uint_as_float(((u32)h) << 16); }

// ============ expand: 3-term hi/lo split (al*bl dropped, ~1e-3 score err) ============
// element e -> slots [3e,3e+2]: A-pattern [ah,ah,al], B-pattern [bh,bl,bh]
// dot over slots = ah*bh + ah*bl + al*bh
__global__ __launch_bounds__(256)
void expand3(const float4* __restrict__ x, u16* __restrict__ out, float scale, int patA) {
  int t = blockIdx.x * 256 + threadIdx.x;      // 524288 threads, 8 floats each
  float4 v0 = x[(size_t)t * 2], v1 = x[(size_t)t * 2 + 1];
  float vv[8] = {v0.x*scale, v0.y*scale, v0.z*scale, v0.w*scale,
                 v1.x*scale, v1.y*scale, v1.z*scale, v1.w*scale};
  u16 o[24];
#pragma unroll
  for (int j = 0; j < 8; ++j) {
    u16 h = f2bf(vv[j]);
    u16 l = f2bf(vv[j] - bf2f(h));             // Sterbenz-exact residual, RNE
    if (patA) { o[3*j]=h; o[3*j+1]=h; o[3*j+2]=l; }
    else      { o[3*j]=h; o[3*j+1]=l; o[3*j+2]=h; }
  }
  u16x8* dst = (u16x8*)(out + (size_t)t * 24);
#pragma unroll
  for (int q = 0; q < 3; ++q) {
    u16x8 w;
#pragma unroll
    for (int j = 0; j < 8; ++j) w[j] = o[q*8+j];
    dst[q] = w;
  }
}

// ============ V transpose to bf16: VT[d][k] = bf16(x2[k][d]) ============
__global__ __launch_bounds__(256)
void transpose_bf16(const float* __restrict__ x2, u16* __restrict__ VT) {
  __shared__ float tile[64][65];
  int tid = threadIdx.x;
  int dt = blockIdx.x;   // 16 D-tiles
  int kt = blockIdx.y;   // 64 K-tiles
#pragma unroll
  for (int it = 0; it < 16; ++it) {
    int lin = it * 256 + tid;
    int r = lin >> 6, c = lin & 63;
    tile[r][c] = x2[(size_t)(kt*64 + r) * DDIM + dt*64 + c];
  }
  __syncthreads();
#pragma unroll
  for (int it = 0; it < 16; ++it) {
    int lin = it * 256 + tid;
    int dr = lin >> 6, kc = lin & 63;
    VT[(size_t)(dt*64 + dr) * MROWS + kt*64 + kc] = f2bf(tile[kc][dr]);
  }
}

// ============ 256x256 8-phase GEMM: C[M,N] = A[M,K] * Bt[N,K]^T ============
// 512 thr (8 waves 2Mx4N), BK=64, dbuf LDS 128KB, chunk-XOR swizzle,
// counted vmcnt(6) at phases 4/8, setprio around MFMA clusters.
__device__ __forceinline__ void gload16(const u16* g, u16* l) {
  __builtin_amdgcn_global_load_lds(
      (const __attribute__((address_space(1))) void*)g,
      (__attribute__((address_space(3))) void*)l, 16, 0, 0);
}

#define BARRIER() do { asm volatile("" ::: "memory"); __builtin_amdgcn_s_barrier(); \
                       asm volatile("" ::: "memory"); } while (0)
#define LGKM0()   do { asm volatile("s_waitcnt lgkmcnt(0)" ::: "memory"); \
                       __builtin_amdgcn_sched_barrier(0); } while (0)
#define VMCNT6()  do { asm volatile("s_waitcnt vmcnt(6)" ::: "memory"); } while (0)

__device__ __forceinline__ void read_a4(bf16x8 (&aF)[4][2], const u16* base, const int (&off)[4][2]) {
#pragma unroll
  for (int m = 0; m < 4; ++m)
#pragma unroll
    for (int kx = 0; kx < 2; ++kx)
      aF[m][kx] = *(const bf16x8*)(base + off[m][kx]);
}
__device__ __forceinline__ void read_b2(bf16x8 (&bF)[2][2], const u16* base, const int (&off)[2][2]) {
#pragma unroll
  for (int n = 0; n < 2; ++n)
#pragma unroll
    for (int kx = 0; kx < 2; ++kx)
      bF[n][kx] = *(const bf16x8*)(base + off[n][kx]);
}
__device__ __forceinline__ void mma_quad(f32x4 (&acc)[8][4], const bf16x8 (&aF)[4][2],
                                         const bf16x8 (&bF)[2][2], int MH, int NH) {
#pragma unroll
  for (int kx = 0; kx < 2; ++kx)
#pragma unroll
    for (int m = 0; m < 4; ++m)
#pragma unroll
      for (int n = 0; n < 2; ++n)
        acc[MH*4+m][NH*2+n] = __builtin_amdgcn_mfma_f32_16x16x32_bf16(
            aF[m][kx], bF[n][kx], acc[MH*4+m][NH*2+n], 0, 0, 0);
}

// LDS u16 layout: A(d,h) = (d*2+h)*8192 ; B(d,h) = 32768 + (d*2+h)*8192
__global__ __launch_bounds__(512, 2)
void gemm256(const u16* __restrict__ A, const u16* __restrict__ Bt, float* __restrict__ C,
             int M, int N, int K, int ntpc) {
  __shared__ u16 smem[65536];   // 128 KiB
  const int tid = threadIdx.x;
  const int lane = tid & 63;
  const int w = tid >> 6;
  const int wr = w >> 2;          // 0..1
  const int wc = w & 3;           // 0..3
  const int fr = lane & 15;
  const int hi = lane >> 4;

  const long bm = (long)blockIdx.y * 256;
  const long bn = (long)blockIdx.x * 256;
  const size_t kcol0 = (size_t)blockIdx.z * ntpc * 64;
  float* Cz = C + (size_t)blockIdx.z * (size_t)M * N;

  // staging: thread -> (row=tid>>3 (+64j,+128h), chunk=tid&7); src chunk pre-swizzled
  const int srow = tid >> 3;
  const int scol = (((tid & 7) ^ (srow & 7)) << 3);
  const u16* Abase = A + (size_t)(bm + srow) * K + kcol0 + scol;
  const u16* Bbase = Bt + (size_t)(bn + srow) * K + kcol0 + scol;

  // per-lane swizzled read offsets (u16 units within a half-tile [128][64])
  int offA[4][2], offB[2][2];
#pragma unroll
  for (int m = 0; m < 4; ++m)
#pragma unroll
    for (int kx = 0; kx < 2; ++kx) {
      int r = m*32 + wr*16 + fr;
      int c0 = kx*4 + hi;
      offA[m][kx] = r*64 + (((c0 ^ (r & 7))) << 3);
    }
#pragma unroll
  for (int n = 0; n < 2; ++n)
#pragma unroll
    for (int kx = 0; kx < 2; ++kx) {
      int r = n*64 + wc*16 + fr;
      int c0 = kx*4 + hi;
      offB[n][kx] = r*64 + (((c0 ^ (r & 7))) << 3);
    }

  f32x4 acc[8][4];
#pragma unroll
  for (int m = 0; m < 8; ++m)
#pragma unroll
    for (int n = 0; n < 4; ++n) acc[m][n] = (f32x4){0.f, 0.f, 0.f, 0.f};
  bf16x8 aF[4][2], b0F[2][2], b1F[2][2];

#define STAGE_A(TAU,H,D) do { \
    const u16* _s = Abase + (size_t)(H)*128*K + (size_t)(TAU)*64; \
    u16* _d = smem + ((D)*2+(H))*8192 + tid*8; \
    gload16(_s, _d); gload16(_s + (size_t)64*K, _d + 4096); } while (0)
#define STAGE_B(TAU,H,D) do { \
    const u16* _s = Bbase + (size_t)(H)*128*K + (size_t)(TAU)*64; \
    u16* _d = smem + 32768 + ((D)*2+(H))*8192 + tid*8; \
    gload16(_s, _d); gload16(_s + (size_t)64*K, _d + 4096); } while (0)

  // ---- prologue: tile0 all 4 halves (oldest 8 loads), then tile1 A0,B0,B1 ----
  STAGE_A(0,0,0); STAGE_B(0,0,0); STAGE_B(0,1,0); STAGE_A(0,1,0);
  STAGE_A(1,0,1); STAGE_B(1,0,1); STAGE_B(1,1,1);
  VMCNT6();                 // tile0 fully landed
  BARRIER();

  const int nt = ntpc;
  for (int T = 0; T < nt; T += 2) {
    const int t1 = T + 1;
    const int t2 = (T + 2 < nt) ? T + 2 : nt - 1;   // tail: dummy re-stage (regions dead)
    const int t3 = (T + 3 < nt) ? T + 3 : nt - 1;

    // p1: quad(0,0) tile T (buf0)
    read_a4(aF, smem + 0, offA);            // A0 b0
    read_b2(b0F, smem + 32768, offB);       // B0 b0
    STAGE_A(t1, 1, 1);                      // A1(T+1) (region freed @p3 prev iter)
    BARRIER(); LGKM0();
    __builtin_amdgcn_s_setprio(1); mma_quad(acc, aF, b0F, 0, 0); __builtin_amdgcn_s_setprio(0);
    BARRIER();
    // p2: quad(0,1)
    read_b2(b1F, smem + 40960, offB);       // B1 b0
    STAGE_A(t2, 0, 0);                      // A0(T+2) (freed @p1)
    BARRIER(); LGKM0();
    __builtin_amdgcn_s_setprio(1); mma_quad(acc, aF, b1F, 0, 1); __builtin_amdgcn_s_setprio(0);
    BARRIER();
    // p3: quad(1,0)
    read_a4(aF, smem + 8192, offA);         // A1 b0
    STAGE_B(t2, 0, 0);                      // B0(T+2) (freed @p1)
    BARRIER(); LGKM0();
    __builtin_amdgcn_s_setprio(1); mma_quad(acc, aF, b0F, 1, 0); __builtin_amdgcn_s_setprio(0);
    BARRIER();
    // p4: quad(1,1)  [vmcnt(6): tile T+1 fully landed before p5]
    STAGE_B(t2, 1, 0);                      // B1(T+2) (freed @p2)
    VMCNT6();
    BARRIER(); LGKM0();
    __builtin_amdgcn_s_setprio(1); mma_quad(acc, aF, b1F, 1, 1); __builtin_amdgcn_s_setprio(0);
    BARRIER();
    // p5: quad(0,0) tile T+1 (buf1)
    read_a4(aF, smem + 16384, offA);        // A0 b1
    read_b2(b0F, smem + 49152, offB);       // B0 b1
    STAGE_A(t2, 1, 0);                      // A1(T+2) (freed @p3)
    BARRIER(); LGKM0();
    __builtin_amdgcn_s_setprio(1); mma_quad(acc, aF, b0F, 0, 0); __builtin_amdgcn_s_setprio(0);
    BARRIER();
    // p6: quad(0,1)
    read_b2(b1F, smem + 57344, offB);       // B1 b1
    STAGE_A(t3, 0, 1);                      // A0(T+3) (freed @p5)
    BARRIER(); LGKM0();
    __builtin_amdgcn_s_setprio(1); mma_quad(acc, aF, b1F, 0, 1); __builtin_amdgcn_s_setprio(0);
    BARRIER();
    // p7: quad(1,0)
    read_a4(aF, smem + 24576, offA);        // A1 b1
    STAGE_B(t3, 0, 1);                      // B0(T+3) (freed @p5)
    BARRIER(); LGKM0();
    __builtin_amdgcn_s_setprio(1); mma_quad(acc, aF, b0F, 1, 0); __builtin_amdgcn_s_setprio(0);
    BARRIER();
    // p8: quad(1,1)  [vmcnt(6): tile T+2 fully landed before p1']
    STAGE_B(t3, 1, 1);                      // B1(T+3) (freed @p6)
    VMCNT6();
    BARRIER(); LGKM0();
    __builtin_amdgcn_s_setprio(1); mma_quad(acc, aF, b1F, 1, 1); __builtin_amdgcn_s_setprio(0);
    BARRIER();
  }
#undef STAGE_A
#undef STAGE_B

  // epilogue: C/D layout col=lane&15, row=(lane>>4)*4+reg  [verified m89/m91, round-1]
#pragma unroll
  for (int m = 0; m < 8; ++m)
#pragma unroll
    for (int n = 0; n < 4; ++n) {
      size_t row0 = (size_t)(bm + m*32 + wr*16 + hi*4);
      size_t col  = (size_t)(bn + n*64 + wc*16 + fr);
#pragma unroll
      for (int r = 0; r < 4; ++r)
        Cz[(row0 + r) * N + col] = acc[m][n][r];
    }
}

// ============ softmax + JAX-threefry dropout -> bf16 P ============
__device__ __forceinline__ u32 rotl32(u32 x, int r) { return (x << r) | (x >> (32 - r)); }

__device__ __forceinline__ u32 threefry_bits(u32 n) {
  const u32 K0 = 0u, K1 = 42u, K2 = 0x1BD11BDAu ^ 0u ^ 42u;
  u32 x0 = K0;
  u32 x1 = n + K1;
#define TF4(a,b,c,d) \
  x0 += x1; x1 = rotl32(x1, a); x1 ^= x0; \
  x0 += x1; x1 = rotl32(x1, b); x1 ^= x0; \
  x0 += x1; x1 = rotl32(x1, c); x1 ^= x0; \
  x0 += x1; x1 = rotl32(x1, d); x1 ^= x0;
  TF4(13,15,26,6);  x0 += K1; x1 += K2 + 1u;
  TF4(17,29,16,24); x0 += K2; x1 += K0 + 2u;
  TF4(13,15,26,6);  x0 += K0; x1 += K1 + 3u;
  TF4(17,29,16,24); x0 += K1; x1 += K2 + 4u;
  TF4(13,15,26,6);  x0 += K2; x1 += K0 + 5u;
#undef TF4
  return x0 ^ x1;
}

__global__ __launch_bounds__(256)
void softmax_dropout(const float* __restrict__ S, u16* __restrict__ P) {
  const int tid  = threadIdx.x;
  const int lane = tid & 63;
  const int w    = tid >> 6;
  const int row  = blockIdx.x * 4 + w;
  const float4* Sr = (const float4*)(S + (size_t)row * MROWS);
  float4 v[16];
#pragma unroll
  for (int i = 0; i < 16; ++i) v[i] = Sr[i * 64 + lane];
  float m = -3.0e38f;
#pragma unroll
  for (int i = 0; i < 16; ++i)
    m = fmaxf(m, fmaxf(fmaxf(v[i].x, v[i].y), fmaxf(v[i].z, v[i].w)));
#pragma unroll
  for (int off = 32; off > 0; off >>= 1) m = fmaxf(m, __shfl_xor(m, off, 64));
  float s = 0.0f;
#pragma unroll
  for (int i = 0; i < 16; ++i) {
    v[i].x = __expf(v[i].x - m); v[i].y = __expf(v[i].y - m);
    v[i].z = __expf(v[i].z - m); v[i].w = __expf(v[i].w - m);
    s += v[i].x + v[i].y + v[i].z + v[i].w;
  }
#pragma unroll
  for (int off = 32; off > 0; off >>= 1) s += __shfl_xor(s, off, 64);
  const float inv = 2.0f / s;            // softmax * 1/(1-p)
  u16* Pr = P + (size_t)row * MROWS;
#pragma unroll
  for (int i = 0; i < 16; ++i) {
    int j0 = (i * 64 + lane) * 4;
    u32 base = (u32)row * 4096u + (u32)j0;
    float e[4] = {v[i].x, v[i].y, v[i].z, v[i].w};
    u16x4 o;
#pragma unroll
    for (int c = 0; c < 4; ++c) {
      u32 bits = threefry_bits(base + (u32)c);
      float val = (bits & 0x80000000u) ? 0.0f : e[c] * inv;   // uniform<0.5 == MSB 0
      o[c] = f2bf(val);
    }
    *(u16x4*)(Pr + j0) = o;
  }
}

// ============ split-K reduction: out = sum of 4 partials ============
__global__ __launch_bounds__(256)
void reduce4(const float4* __restrict__ p, float4* __restrict__ out) {
  size_t i = (size_t)blockIdx.x * 256 + threadIdx.x;
  const size_t NP = (size_t)MROWS * DDIM / 4;
  float4 a = p[i], b = p[i + NP], c = p[i + 2*NP], d = p[i + 3*NP];
  float4 r;
  r.x = a.x + b.x + c.x + d.x;
  r.y = a.y + b.y + c.y + d.y;
  r.z = a.z + b.z + c.z + d.z;
  r.w = a.w + b.w + c.w + d.w;
  out[i] = r;
}

// ============ launch ============
extern "C" void kernel_launch(void* const* d_in, const int* in_sizes, int n_in,
                              void* d_out, int out_size, void* d_ws, size_t ws_size,
                              hipStream_t stream) {
  const float* x1 = (const float*)d_in[0];
  const float* x2 = (const float*)d_in[1];
  float* out = (float*)d_out;
  char* ws = (char*)d_ws;

  // ws layout (bytes):
  //   XA [0,24M) | XB [24M,48M) | VT [48M,56M) | S [56M,120M)
  //   P (32M) overlays XA+XB after GEMM1 ; partials (64M) overlay S after softmax
  const size_t OFF_XB = 25165824;
  const size_t OFF_VT = 50331648;
  const size_t OFF_S  = 58720256;
  const size_t NEED   = 125829120;
  if (ws_size < NEED) {
    hipMemsetAsync(d_out, 0x7F, (size_t)out_size * sizeof(float), stream);
    return;
  }
  u16*   XA = (u16*)(ws);
  u16*   XB = (u16*)(ws + OFF_XB);
  u16*   VT = (u16*)(ws + OFF_VT);
  float* S  = (float*)(ws + OFF_S);
  float* PT = (float*)(ws + OFF_S);   // partials reuse S
  u16*   P  = (u16*)(ws);             // reuses XA(+XB) region

  expand3<<<2048, 256, 0, stream>>>((const float4*)x1, XA, 4.0f, 1);  // scale folded into x1
  expand3<<<2048, 256, 0, stream>>>((const float4*)x2, XB, 1.0f, 0);
  transpose_bf16<<<dim3(16, 64), 256, 0, stream>>>(x2, VT);
  // S = (4*x1) @ x2^T via 3-term expanded K = 3072
  gemm256<<<dim3(16, 16, 1), 512, 0, stream>>>(XA, XB, S, 4096, 4096, 3072, 48);
  softmax_dropout<<<1024, 256, 0, stream>>>(S, P);
  // O = P @ V: split-K x4 (K=4096, 16 tiles/chunk), then reduce
  gemm256<<<dim3(4, 16, 4), 512, 0, stream>>>(P, VT, PT, 4096, 1024, 4096, 16);
  reduce4<<<4096, 256, 0, stream>>>((const float4*)PT, (float4*)out);
}